// Round 10
// baseline (120.255 us; speedup 1.0000x reference)
//
#include <hip/hip_runtime.h>
#include <math.h>

#define NB    8
#define NN    100
#define NPRED 800
#define MT    20
#define NT    160
#define HW    25600
#define NCLS  80
#define CNT   (NPRED*NT)  // 128000
#define MTILES 13

typedef float  f32x4  __attribute__((ext_vector_type(4)));
typedef short  short8 __attribute__((ext_vector_type(8)));
typedef unsigned short u16x8 __attribute__((ext_vector_type(8)));

static __device__ __forceinline__ unsigned short f2bf_rne(float f){
  unsigned u = __float_as_uint(f);
  return (unsigned short)((u + 0x7fffu + ((u >> 16) & 1u)) >> 16);
}

// async global->LDS, 16B per lane
static __device__ __forceinline__ void gload16(const void* g, void* l){
  __builtin_amdgcn_global_load_lds((const __attribute__((address_space(1))) unsigned int*)g,
                                   (__attribute__((address_space(3))) unsigned int*)l, 16, 0, 0);
}

// ---------------- pre-pass: tm fp32 -> bf16 with BAKED XOR swizzle, half-row partial tnorm ----------------
// grid 320: block = (row, half). tnp2[half*160+row] partials summed in norm_reduce.
__global__ __launch_bounds__(256)
void conv_b(const float* __restrict__ tm, unsigned short* __restrict__ Bb,
            float* __restrict__ tnp2){
  const int row = blockIdx.x >> 1, half = blockIdx.x & 1;
  const float4* src = (const float4*)(tm + (size_t)row * HW);
  u16x8* dst = (u16x8*)(Bb + (size_t)row * HW);
  const int sw = row & 7;
  const int g0 = half * 1600, g1 = g0 + 1600;        // of 3200 granules
  float s = 0.f;
  for (int g = g0 + threadIdx.x; g < g1; g += 256){
    float4 x0 = src[g * 2], x1 = src[g * 2 + 1];
    float v[8];
    v[0]=x0.x; v[1]=x0.y; v[2]=x0.z; v[3]=x0.w;
    v[4]=x1.x; v[5]=x1.y; v[6]=x1.z; v[7]=x1.w;
    u16x8 h;
    #pragma unroll
    for (int i = 0; i < 8; i++){ s += v[i]*v[i]; h[i] = f2bf_rne(v[i]); }
    dst[(g & ~7) | ((g & 7) ^ sw)] = h;
  }
  __shared__ float red[256];
  red[threadIdx.x] = s; __syncthreads();
  for (int off = 128; off > 0; off >>= 1){
    if (threadIdx.x < off) red[threadIdx.x] += red[threadIdx.x + off];
    __syncthreads();
  }
  if (threadIdx.x == 0) tnp2[half * NT + row] = red[0];
}

// ---------------- hybrid GEMM (r8 structure): A fp32->cvt->ds_write, B via global_load_lds ----------------
// Tile 64x160x64; 4 waves 2x2, wave tile 32x80 (2x5 frags of 16x16x32 bf16).
// LDS bf16 with (granule ^ (row&7)) swizzle -> 0 bank conflicts. 28 KiB -> 4 blocks/CU.
template<int KSTEPS>
__global__ __launch_bounds__(256, 4)
void gemm_hyb(const float* __restrict__ A, const unsigned short* __restrict__ Bb,
              float* __restrict__ part, float* __restrict__ pnp, int Kc){
  __shared__ unsigned short sA[64*64];    // 8 KB
  __shared__ unsigned short sB[160*64];   // 20 KB

  const int bid = blockIdx.x;
  const int nb  = gridDim.x;
  const int wg  = ((nb & 7) == 0) ? (bid & 7) * (nb >> 3) + (bid >> 3) : bid;  // XCD-bijective
  const int mtile = wg % MTILES, ks = wg / MTILES;
  const int t = threadIdx.x, lane = t & 63, w = t >> 6;
  const int wr = w >> 1, wc = w & 1;
  const int fr = lane & 15, fq = lane >> 4;
  const int r0 = t >> 3, ksl = t & 7;
  const int kbase = ks * Kc;

  bool aok[2];
  #pragma unroll
  for (int j = 0; j < 2; j++) aok[j] = (mtile * 64 + r0 + 32 * j) < NPRED;

  f32x4 acc[2][5];
  #pragma unroll
  for (int r = 0; r < 2; r++)
    #pragma unroll
    for (int c = 0; c < 5; c++) acc[r][c] = (f32x4){0.f,0.f,0.f,0.f};
  float asum[2] = {0.f, 0.f};

  // B slot descriptors: 1280 granules, 5 per thread
  int brow[5], bg[5];
  #pragma unroll
  for (int i = 0; i < 5; i++){ int s2 = t + i * 256; brow[i] = s2 >> 3; bg[i] = s2 & 7; }

  for (int step = 0; step < KSTEPS; ++step){
    const int k0 = kbase + step * 64;
    // ---- B: direct DMA to linear LDS (swizzle baked in memory) ----
    #pragma unroll
    for (int i = 0; i < 5; i++)
      gload16(Bb + (size_t)brow[i] * HW + k0 + bg[i] * 8, sB + (t + i * 256) * 8);
    // ---- A: fp32 load -> cvt -> swizzled ds_write ----
    #pragma unroll
    for (int j = 0; j < 2; ++j){
      const int row = r0 + 32 * j;
      float v[8];
      if (aok[j]){
        const float4* p = (const float4*)(A + (size_t)(mtile*64 + row) * HW + k0 + ksl * 8);
        float4 x0 = p[0], x1 = p[1];
        v[0]=x0.x; v[1]=x0.y; v[2]=x0.z; v[3]=x0.w;
        v[4]=x1.x; v[5]=x1.y; v[6]=x1.z; v[7]=x1.w;
      } else {
        #pragma unroll
        for (int i = 0; i < 8; i++) v[i] = 0.f;
      }
      u16x8 h;
      #pragma unroll
      for (int i = 0; i < 8; i++){ asum[j] += v[i]*v[i]; h[i] = f2bf_rne(v[i]); }
      *(u16x8*)&sA[row * 64 + ((ksl ^ (row & 7)) << 3)] = h;
    }
    __syncthreads();   // drains vmcnt (B DMA) + lgkmcnt (A writes)
    // ---- MFMA: 2 kk halves x (2x5 frags) ----
    #pragma unroll
    for (int kk = 0; kk < 2; ++kk){
      const int swz = (((kk * 4 + fq) ^ (fr & 7)) << 3);
      short8 a[2], b[5];
      #pragma unroll
      for (int r = 0; r < 2; r++)
        a[r] = *(const short8*)&sA[(wr*32 + r*16 + fr) * 64 + swz];
      #pragma unroll
      for (int c = 0; c < 5; c++)
        b[c] = *(const short8*)&sB[(wc*80 + c*16 + fr) * 64 + swz];
      #pragma unroll
      for (int r = 0; r < 2; r++)
        #pragma unroll
        for (int c = 0; c < 5; c++)
          acc[r][c] = __builtin_amdgcn_mfma_f32_16x16x32_bf16(a[r], b[c], acc[r][c], 0, 0, 0);
    }
    __syncthreads();
  }

  // ---- pnorm partials: reduce over ksl lanes ----
  #pragma unroll
  for (int j = 0; j < 2; ++j){
    float s = asum[j];
    s += __shfl_xor(s, 1); s += __shfl_xor(s, 2); s += __shfl_xor(s, 4);
    const int grow = mtile*64 + r0 + 32*j;
    if ((t & 7) == 0 && grow < NPRED) pnp[(size_t)ks * NPRED + grow] = s;
  }

  // ---- store partials ----
  float* dst = part + (size_t)ks * CNT;
  #pragma unroll
  for (int r = 0; r < 2; r++)
    #pragma unroll
    for (int c = 0; c < 5; c++)
      #pragma unroll
      for (int i = 0; i < 4; i++){
        const int grow = mtile*64 + wr*32 + r*16 + fq*4 + i;
        if (grow < NPRED)
          dst[(size_t)grow * NT + wc*80 + c*16 + fr] = acc[r][c][i];
      }
}

// ---------------- reduce pnorm partials + tnorm halves ----------------
__global__ __launch_bounds__(256) void norm_reduce(const float* __restrict__ pnp,
                                                   const float* __restrict__ tnp2,
                                                   float* __restrict__ pn,
                                                   float* __restrict__ tn, int KS){
  int idx = blockIdx.x * 256 + threadIdx.x;
  if (idx < NPRED){
    float s = 0.f;
    for (int ks = 0; ks < KS; ks++) s += pnp[(size_t)ks * NPRED + idx];
    pn[idx] = s;
  } else if (idx < NPRED + NT){
    int j = idx - NPRED;
    tn[j] = tnp2[j] + tnp2[NT + j];
  }
}

// ---------------- finalize: reduce K-splits, dice + focal class cost ----------------
__global__ __launch_bounds__(256) void finalize(const float* __restrict__ part, int KS,
                                                const float* __restrict__ pnorm,
                                                const float* __restrict__ tnorm,
                                                const float* __restrict__ logits,
                                                const int* __restrict__ tgt_ids,
                                                float* __restrict__ C){
  int idx = blockIdx.x * 256 + threadIdx.x;
  int pred = idx / NT, tt = idx - pred * NT;
  const float* p = part + idx;
  double d0=0.0, d1=0.0, d2=0.0, d3=0.0;
  int ks = 0;
  for (; ks + 4 <= KS; ks += 4){
    d0 += (double)p[(size_t)(ks+0) * CNT];
    d1 += (double)p[(size_t)(ks+1) * CNT];
    d2 += (double)p[(size_t)(ks+2) * CNT];
    d3 += (double)p[(size_t)(ks+3) * CNT];
  }
  for (; ks < KS; ks++) d0 += (double)p[(size_t)ks * CNT];
  double dot = (d0 + d1) + (d2 + d3);
  double num = 2.0 * dot;
  double den = (double)pnorm[pred] + (double)tnorm[tt];
  double mask_score = -((num + 1e-4) / (den + 1e-4));
  double x = (double)logits[pred * NCLS + tgt_ids[tt]];
  double pl = 1.0 / (1.0 + exp(-x));
  double pos = 0.25 * (1.0 - pl) * (1.0 - pl) * (-log(pl + 1e-8));
  double neg = 0.75 * pl * pl * (-log(1.0 - pl + 1e-8));
  double cv = mask_score * 2.0 + (pos - neg);
  float o = (float)cv;
  if (!isfinite(o)) o = 0.0f;
  C[idx] = o;
}

// ---------------- Hungarian (JV): packed (p,u) lookup + scalar matched-mask break ----------------
static __device__ __forceinline__ float sel20(const float c[20], int k){
  const bool b0 = k & 1, b1 = k & 2;
  float t0 = b0 ? c[1]  : c[0],  t1 = b0 ? c[3]  : c[2];
  float t2 = b0 ? c[5]  : c[4],  t3 = b0 ? c[7]  : c[6];
  float t4 = b0 ? c[9]  : c[8],  t5 = b0 ? c[11] : c[10];
  float t6 = b0 ? c[13] : c[12], t7 = b0 ? c[15] : c[14];
  float t8 = b0 ? c[17] : c[16], t9 = b0 ? c[19] : c[18];
  float e0 = b1 ? t1 : t0, e1 = b1 ? t3 : t2, e2 = b1 ? t5 : t4;
  float e3 = b1 ? t7 : t6, e4 = b1 ? t9 : t8;
  const int hi = k >> 2;
  const bool h0 = hi & 1, h1 = hi & 2, h2 = hi & 4;
  float g0 = h0 ? e1 : e0, g1 = h0 ? e3 : e2;
  float m0 = h1 ? g1 : g0;
  return h2 ? e4 : m0;
}

static __device__ __forceinline__ float dppmin(float v, int ctrl){
  int x;
  switch (ctrl){
    case 0xB1:  x = __builtin_amdgcn_update_dpp(0, __float_as_int(v), 0xB1,  0xF, 0xF, true); break;
    case 0x4E:  x = __builtin_amdgcn_update_dpp(0, __float_as_int(v), 0x4E,  0xF, 0xF, true); break;
    case 0x124: x = __builtin_amdgcn_update_dpp(0, __float_as_int(v), 0x124, 0xF, 0xF, true); break;
    default:    x = __builtin_amdgcn_update_dpp(0, __float_as_int(v), 0x128, 0xF, 0xF, true); break;
  }
  return fminf(v, __int_as_float(x));
}

__global__ __launch_bounds__(64) void hungarian(const float* __restrict__ C,
                                                float* __restrict__ rows_out,
                                                float* __restrict__ cols_out){
  const int img  = blockIdx.x;
  const int lane = threadIdx.x;
  const int jA = lane + 1, jB = lane + 65;
  const bool hasB = (jB <= NN);

  float ca[20], cb[20];
  {
    const float* basep = C + (size_t)img * NN * NT + (size_t)lane * NT + img * MT;
    #pragma unroll
    for (int r = 0; r < 5; r++){
      float4 x = *(const float4*)(basep + r*4);
      ca[r*4+0]=x.x; ca[r*4+1]=x.y; ca[r*4+2]=x.z; ca[r*4+3]=x.w;
    }
    if (hasB){
      const float* basep2 = basep + (size_t)64 * NT;
      #pragma unroll
      for (int r = 0; r < 5; r++){
        float4 x = *(const float4*)(basep2 + r*4);
        cb[r*4+0]=x.x; cb[r*4+1]=x.y; cb[r*4+2]=x.z; cb[r*4+3]=x.w;
      }
    } else {
      #pragma unroll
      for (int r = 0; r < 20; r++) cb[r] = 0.f;
    }
  }

  const float INF = 1e30f;
  float vA = 0.f, vB = 0.f;
  float uA = 0.f, uB = 0.f;     // u of the row matched to this lane's col
  int pA = 0, pB = 0;
  unsigned long long mAmask = 0ull, mBmask = 0ull;   // matched-col masks

  for (int i = 1; i <= MT; i++){
    float minA = INF, minB = INF;
    int wayA = 0, wayB = 0;
    bool usedA = false, usedB = false;
    float u_i = 0.f;
    int j0 = 0, i0 = i;
    float ui0 = 0.f;

    while (true){
      if (j0 != 0){
        if (j0 <= 64){ if (lane == j0 - 1)  usedA = true; }
        else         { if (lane == j0 - 65) usedB = true; }
      }
      if (!usedA){
        float cur = sel20(ca, i0 - 1) - ui0 - vA;
        if (cur < minA){ minA = cur; wayA = j0; }
      }
      if (hasB && !usedB){
        float cur = sel20(cb, i0 - 1) - ui0 - vB;
        if (cur < minB){ minB = cur; wayB = j0; }
      }
      float candA = usedA ? INF : minA;
      float candB = (hasB && !usedB) ? minB : INF;
      float v = fminf(candA, candB);
      v = dppmin(v, 0xB1);
      v = dppmin(v, 0x4E);
      v = dppmin(v, 0x124);
      v = dppmin(v, 0x128);
      v = fminf(v, __shfl_xor(v, 16));
      v = fminf(v, __shfl_xor(v, 32));
      const float delta = v;
      unsigned long long mAm = __ballot(candA == delta);
      unsigned long long mBm = __ballot(candB == delta);
      const int j1 = mAm ? __ffsll(mAm) : 64 + __ffsll(mBm);
      u_i += delta;
      if (usedA){ vA -= delta; uA += delta; } else minA -= delta;
      if (hasB){ if (usedB){ vB -= delta; uB += delta; } else minB -= delta; }
      j0 = j1;
      bool matched = (j0 <= 64) ? ((mAmask >> (j0 - 1)) & 1ull)
                                : ((mBmask >> (j0 - 65)) & 1ull);
      int   pa = __shfl(pA, (j0 - 1) & 63), pb = __shfl(pB, (j0 - 65) & 63);
      float ua = __shfl(uA, (j0 - 1) & 63), ub = __shfl(uB, (j0 - 65) & 63);
      if (!matched) break;
      i0  = (j0 <= 64) ? pa : pb;
      ui0 = (j0 <= 64) ? ua : ub;
    }
    int j = j0;
    while (true){
      int wjA = __shfl(wayA, (j - 1) & 63);
      int wjB = __shfl(wayB, (j - 65) & 63);
      int wj = (j <= 64) ? wjA : wjB;
      int pv; float uv;
      if (wj == 0){ pv = i; uv = u_i; }
      else {
        int   pa = __shfl(pA, (wj - 1) & 63), pb = __shfl(pB, (wj - 65) & 63);
        float ua = __shfl(uA, (wj - 1) & 63), ub = __shfl(uB, (wj - 65) & 63);
        pv = (wj <= 64) ? pa : pb;
        uv = (wj <= 64) ? ua : ub;
      }
      if (j <= 64){ if (lane == j - 1) { pA = pv; uA = uv; } }
      else        { if (lane == j - 65){ pB = pv; uB = uv; } }
      j = wj;
      if (j == 0) break;
    }
    mAmask = __ballot(pA != 0);
    mBmask = __ballot(hasB && pB != 0);
  }

  unsigned long long lt = (1ull << lane) - 1ull;
  if (pA != 0){
    int rank = __popcll(mAmask & lt);
    rows_out[img * MT + rank] = (float)(jA - 1);
    cols_out[img * MT + rank] = (float)(pA - 1);
  }
  if (hasB && pB != 0){
    int rank = __popcll(mAmask) + __popcll(mBmask & lt);
    rows_out[img * MT + rank] = (float)(jB - 1);
    cols_out[img * MT + rank] = (float)(pB - 1);
  }
}

extern "C" void kernel_launch(void* const* d_in, const int* in_sizes, int n_in,
                              void* d_out, int out_size, void* d_ws, size_t ws_size,
                              hipStream_t stream) {
  const float* pm     = (const float*)d_in[0];
  const float* logits = (const float*)d_in[1];
  const float* tm     = (const float*)d_in[2];
  const int*   tids   = (const int*)d_in[3];

  float* C        = (float*)d_out;
  float* rows_out = C + CNT;
  float* cols_out = rows_out + NB * MT;

  // ws: pnp[KS][800] | pnorm[800] | tnorm[160] | tnp2[320] | Bb bf16[160*25600] | part[KS][128000]
  static const int ks_opts[] = {80, 40, 20};
  int KS = 20; size_t bb_off = 0, part_off = 0;
  for (int oi = 0; oi < 3; oi++){
    int o = ks_opts[oi];
    size_t small = (size_t)o * NPRED * 4 + NPRED * 4 + NT * 4 + 2 * NT * 4;
    size_t bo = (small + 255) & ~(size_t)255;
    size_t po = (bo + (size_t)NT * HW * 2 + 255) & ~(size_t)255;
    size_t need = po + (size_t)o * CNT * 4;
    if (need <= ws_size){ KS = o; bb_off = bo; part_off = po; break; }
  }
  char* ws = (char*)d_ws;
  float* pnp         = (float*)ws;
  float* pnorm       = (float*)(ws + (size_t)KS * NPRED * 4);
  float* tnorm       = pnorm + NPRED;
  float* tnp2        = tnorm + NT;
  unsigned short* Bb = (unsigned short*)(ws + bb_off);
  float* part        = (float*)(ws + part_off);

  const int Kc = HW / KS;

  conv_b<<<2 * NT, 256, 0, stream>>>(tm, Bb, tnp2);
  if (KS == 80)      gemm_hyb<5><<<MTILES * 80, 256, 0, stream>>>(pm, Bb, part, pnp, Kc);
  else if (KS == 40) gemm_hyb<10><<<MTILES * 40, 256, 0, stream>>>(pm, Bb, part, pnp, Kc);
  else               gemm_hyb<20><<<MTILES * 20, 256, 0, stream>>>(pm, Bb, part, pnp, Kc);
  norm_reduce<<<4, 256, 0, stream>>>(pnp, tnp2, pnorm, tnorm, KS);
  finalize<<<500, 256, 0, stream>>>(part, KS, pnorm, tnorm, logits, tids, C);
  hungarian<<<NB, 64, 0, stream>>>(C, rows_out, cols_out);
}

// Round 11
// 114.539 us; speedup vs baseline: 1.0499x; 1.0499x over previous
//
#include <hip/hip_runtime.h>
#include <math.h>

#define NB    8
#define NN    100
#define NPRED 800
#define MT    20
#define NT    160
#define HW    25600
#define NCLS  80
#define CNT   (NPRED*NT)  // 128000
#define MTILES 13

typedef float  f32x4  __attribute__((ext_vector_type(4)));
typedef short  short8 __attribute__((ext_vector_type(8)));
typedef unsigned short u16x8 __attribute__((ext_vector_type(8)));

static __device__ __forceinline__ unsigned short f2bf_rne(float f){
  unsigned u = __float_as_uint(f);
  return (unsigned short)((u + 0x7fffu + ((u >> 16) & 1u)) >> 16);
}

// async global->LDS, 16B per lane
static __device__ __forceinline__ void gload16(const void* g, void* l){
  __builtin_amdgcn_global_load_lds((const __attribute__((address_space(1))) unsigned int*)g,
                                   (__attribute__((address_space(3))) unsigned int*)l, 16, 0, 0);
}

// ---------------- pre-pass: tm fp32 -> bf16 with BAKED XOR swizzle, half-row partial tnorm ----------------
__global__ __launch_bounds__(256)
void conv_b(const float* __restrict__ tm, unsigned short* __restrict__ Bb,
            float* __restrict__ tnp2){
  const int row = blockIdx.x >> 1, half = blockIdx.x & 1;
  const float4* src = (const float4*)(tm + (size_t)row * HW);
  u16x8* dst = (u16x8*)(Bb + (size_t)row * HW);
  const int sw = row & 7;
  const int g0 = half * 1600, g1 = g0 + 1600;
  float s = 0.f;
  for (int g = g0 + threadIdx.x; g < g1; g += 256){
    float4 x0 = src[g * 2], x1 = src[g * 2 + 1];
    float v[8];
    v[0]=x0.x; v[1]=x0.y; v[2]=x0.z; v[3]=x0.w;
    v[4]=x1.x; v[5]=x1.y; v[6]=x1.z; v[7]=x1.w;
    u16x8 h;
    #pragma unroll
    for (int i = 0; i < 8; i++){ s += v[i]*v[i]; h[i] = f2bf_rne(v[i]); }
    dst[(g & ~7) | ((g & 7) ^ sw)] = h;
  }
  __shared__ float red[256];
  red[threadIdx.x] = s; __syncthreads();
  for (int off = 128; off > 0; off >>= 1){
    if (threadIdx.x < off) red[threadIdx.x] += red[threadIdx.x + off];
    __syncthreads();
  }
  if (threadIdx.x == 0) tnp2[half * NT + row] = red[0];
}

// ---------------- 2-phase pipelined GEMM, alias-clean double buffers ----------------
// Tile 64x160x64; 4 waves 2x2, wave tile 32x80. Four DISTINCT __shared__ arrays so the
// compiler does NOT vmcnt-drain before ds_reads of the current buffer (r9 failure mode).
#define ISSUE_AB(K0, SBN) do {                                                          \
  _Pragma("unroll")                                                                     \
  for (int j = 0; j < 2; ++j){                                                          \
    if (aok[j]){                                                                        \
      const float4* p = (const float4*)(A + (size_t)(mtile*64 + r0 + 32*j) * HW + (K0) + ksl * 8); \
      av0[j] = p[0]; av1[j] = p[1];                                                     \
    } else { av0[j] = (float4){0,0,0,0}; av1[j] = (float4){0,0,0,0}; }                  \
  }                                                                                     \
  _Pragma("unroll")                                                                     \
  for (int i = 0; i < 5; i++)                                                           \
    gload16(Bb + (size_t)brow[i] * HW + (K0) + bg[i] * 8, SBN + (t + i * 256) * 8);     \
} while(0)

#define CVT_A(SAN) do {                                                                 \
  _Pragma("unroll")                                                                     \
  for (int j = 0; j < 2; ++j){                                                          \
    float v[8];                                                                         \
    v[0]=av0[j].x; v[1]=av0[j].y; v[2]=av0[j].z; v[3]=av0[j].w;                         \
    v[4]=av1[j].x; v[5]=av1[j].y; v[6]=av1[j].z; v[7]=av1[j].w;                         \
    u16x8 h;                                                                            \
    _Pragma("unroll")                                                                   \
    for (int i = 0; i < 8; i++){ asum[j] += v[i]*v[i]; h[i] = f2bf_rne(v[i]); }         \
    const int row_ = r0 + 32 * j;                                                       \
    *(u16x8*)&SAN[row_ * 64 + ((ksl ^ (row_ & 7)) << 3)] = h;                           \
  }                                                                                     \
} while(0)

#define MFMA_PH(SAC, SBC) do {                                                          \
  _Pragma("unroll")                                                                     \
  for (int kk = 0; kk < 2; ++kk){                                                       \
    const int swz = (((kk * 4 + fq) ^ (fr & 7)) << 3);                                  \
    short8 a_[2], b_[5];                                                                \
    _Pragma("unroll")                                                                   \
    for (int r = 0; r < 2; r++)                                                         \
      a_[r] = *(const short8*)&SAC[(wr*32 + r*16 + fr) * 64 + swz];                     \
    _Pragma("unroll")                                                                   \
    for (int c = 0; c < 5; c++)                                                         \
      b_[c] = *(const short8*)&SBC[(wc*80 + c*16 + fr) * 64 + swz];                     \
    _Pragma("unroll")                                                                   \
    for (int r = 0; r < 2; r++)                                                         \
      _Pragma("unroll")                                                                 \
      for (int c = 0; c < 5; c++)                                                       \
        acc[r][c] = __builtin_amdgcn_mfma_f32_16x16x32_bf16(a_[r], b_[c], acc[r][c], 0, 0, 0); \
  }                                                                                     \
} while(0)

template<int KSTEPS>
__global__ __launch_bounds__(256, 2)
void gemm_p2(const float* __restrict__ A, const unsigned short* __restrict__ Bb,
             float* __restrict__ part, float* __restrict__ pnp, int Kc){
  __shared__ unsigned short sA0[64*64], sA1[64*64];     // 8 + 8 KB
  __shared__ unsigned short sB0[160*64], sB1[160*64];   // 20 + 20 KB

  const int bid = blockIdx.x;
  const int nb  = gridDim.x;
  const int wg  = ((nb & 7) == 0) ? (bid & 7) * (nb >> 3) + (bid >> 3) : bid;  // XCD-bijective
  const int mtile = wg % MTILES, ks = wg / MTILES;
  const int t = threadIdx.x, lane = t & 63, w = t >> 6;
  const int wr = w >> 1, wc = w & 1;
  const int fr = lane & 15, fq = lane >> 4;
  const int r0 = t >> 3, ksl = t & 7;
  const int kbase = ks * Kc;

  bool aok[2];
  #pragma unroll
  for (int j = 0; j < 2; j++) aok[j] = (mtile * 64 + r0 + 32 * j) < NPRED;

  int brow[5], bg[5];
  #pragma unroll
  for (int i = 0; i < 5; i++){ int s2 = t + i * 256; brow[i] = s2 >> 3; bg[i] = s2 & 7; }

  f32x4 acc[2][5];
  #pragma unroll
  for (int r = 0; r < 2; r++)
    #pragma unroll
    for (int c = 0; c < 5; c++) acc[r][c] = (f32x4){0.f,0.f,0.f,0.f};
  float asum[2] = {0.f, 0.f};
  float4 av0[2], av1[2];

  // prologue: stage step 0 into buf0
  ISSUE_AB(kbase, sB0);
  CVT_A(sA0);
  __syncthreads();

  #pragma unroll
  for (int s = 0; s < KSTEPS; s += 2){
    const bool st1 = (s + 1 < KSTEPS);
    // even half: stage s+1 into buf1, compute buf0
    if (st1) ISSUE_AB(kbase + (s + 1) * 64, sB1);
    MFMA_PH(sA0, sB0);
    if (st1) CVT_A(sA1);
    __syncthreads();
    if (st1){
      const bool st2 = (s + 2 < KSTEPS);
      // odd half: stage s+2 into buf0, compute buf1
      if (st2) ISSUE_AB(kbase + (s + 2) * 64, sB0);
      MFMA_PH(sA1, sB1);
      if (st2) CVT_A(sA0);
      __syncthreads();
    }
  }

  // pnorm partials
  #pragma unroll
  for (int j = 0; j < 2; ++j){
    float s = asum[j];
    s += __shfl_xor(s, 1); s += __shfl_xor(s, 2); s += __shfl_xor(s, 4);
    const int grow = mtile*64 + r0 + 32*j;
    if ((t & 7) == 0 && grow < NPRED) pnp[(size_t)ks * NPRED + grow] = s;
  }

  // store partials
  float* dst = part + (size_t)ks * CNT;
  #pragma unroll
  for (int r = 0; r < 2; r++)
    #pragma unroll
    for (int c = 0; c < 5; c++)
      #pragma unroll
      for (int i = 0; i < 4; i++){
        const int grow = mtile*64 + wr*32 + r*16 + fq*4 + i;
        if (grow < NPRED)
          dst[(size_t)grow * NT + wc*80 + c*16 + fr] = acc[r][c][i];
      }
}

// ---------------- reduce pnorm partials + tnorm halves ----------------
__global__ __launch_bounds__(256) void norm_reduce(const float* __restrict__ pnp,
                                                   const float* __restrict__ tnp2,
                                                   float* __restrict__ pn,
                                                   float* __restrict__ tn, int KS){
  int idx = blockIdx.x * 256 + threadIdx.x;
  if (idx < NPRED){
    float s = 0.f;
    for (int ks = 0; ks < KS; ks++) s += pnp[(size_t)ks * NPRED + idx];
    pn[idx] = s;
  } else if (idx < NPRED + NT){
    int j = idx - NPRED;
    tn[j] = tnp2[j] + tnp2[NT + j];
  }
}

// shared fp64 reduction: identical op order in both fused roles -> bit-exact
static __device__ __forceinline__ double ks_dot(const float* __restrict__ part, int KS, size_t idx){
  const float* p = part + idx;
  double d0=0.0, d1=0.0, d2=0.0, d3=0.0;
  int ks = 0;
  for (; ks + 4 <= KS; ks += 4){
    d0 += (double)p[(size_t)(ks+0) * CNT];
    d1 += (double)p[(size_t)(ks+1) * CNT];
    d2 += (double)p[(size_t)(ks+2) * CNT];
    d3 += (double)p[(size_t)(ks+3) * CNT];
  }
  for (; ks < KS; ks++) d0 += (double)p[(size_t)ks * CNT];
  return (d0 + d1) + (d2 + d3);
}

static __device__ __forceinline__ float cost_entry(double dot, double pn, double tn, double x){
  double num = 2.0 * dot;
  double den = pn + tn;
  double mask_score = -((num + 1e-4) / (den + 1e-4));
  double pl = 1.0 / (1.0 + exp(-x));
  double pos = 0.25 * (1.0 - pl) * (1.0 - pl) * (-log(pl + 1e-8));
  double neg = 0.75 * pl * pl * (-log(1.0 - pl + 1e-8));
  double cv = mask_score * 2.0 + (pos - neg);
  float o = (float)cv;
  if (!isfinite(o)) o = 0.0f;
  return o;
}

// ---------------- Hungarian helpers ----------------
static __device__ __forceinline__ float sel20(const float c[20], int k){
  const bool b0 = k & 1, b1 = k & 2;
  float t0 = b0 ? c[1]  : c[0],  t1 = b0 ? c[3]  : c[2];
  float t2 = b0 ? c[5]  : c[4],  t3 = b0 ? c[7]  : c[6];
  float t4 = b0 ? c[9]  : c[8],  t5 = b0 ? c[11] : c[10];
  float t6 = b0 ? c[13] : c[12], t7 = b0 ? c[15] : c[14];
  float t8 = b0 ? c[17] : c[16], t9 = b0 ? c[19] : c[18];
  float e0 = b1 ? t1 : t0, e1 = b1 ? t3 : t2, e2 = b1 ? t5 : t4;
  float e3 = b1 ? t7 : t6, e4 = b1 ? t9 : t8;
  const int hi = k >> 2;
  const bool h0 = hi & 1, h1 = hi & 2, h2 = hi & 4;
  float g0 = h0 ? e1 : e0, g1 = h0 ? e3 : e2;
  float m0 = h1 ? g1 : g0;
  return h2 ? e4 : m0;
}

static __device__ __forceinline__ float dppmin(float v, int ctrl){
  int x;
  switch (ctrl){
    case 0xB1:  x = __builtin_amdgcn_update_dpp(0, __float_as_int(v), 0xB1,  0xF, 0xF, true); break;
    case 0x4E:  x = __builtin_amdgcn_update_dpp(0, __float_as_int(v), 0x4E,  0xF, 0xF, true); break;
    case 0x124: x = __builtin_amdgcn_update_dpp(0, __float_as_int(v), 0x124, 0xF, 0xF, true); break;
    default:    x = __builtin_amdgcn_update_dpp(0, __float_as_int(v), 0x128, 0xF, 0xF, true); break;
  }
  return fminf(v, __int_as_float(x));
}

// ---------------- fused finalize + hungarian ----------------
// blocks [0,8): per-image JV (recomputes own 20x100 block bit-identically).
// blocks [8,508): finalize C.
__global__ __launch_bounds__(256)
void fin_hung(const float* __restrict__ part, int KS,
              const float* __restrict__ pnorm, const float* __restrict__ tnorm,
              const float* __restrict__ logits, const int* __restrict__ tgt_ids,
              float* __restrict__ C, float* __restrict__ rows_out,
              float* __restrict__ cols_out){
  const int blk = blockIdx.x;
  const int t = threadIdx.x;
  if (blk >= NB){
    const int idx = (blk - NB) * 256 + t;
    const int pred = idx / NT, tt = idx - pred * NT;
    double dot = ks_dot(part, KS, idx);
    double x = (double)logits[pred * NCLS + tgt_ids[tt]];
    C[idx] = cost_entry(dot, (double)pnorm[pred], (double)tnorm[tt], x);
    return;
  }

  const int img = blk;
  __shared__ float cost[MT][NN];
  for (int e = t; e < MT * NN; e += 256){
    const int p = e / MT, tt = e - p * MT;
    const int gp = img * NN + p, gt = img * MT + tt;
    double dot = ks_dot(part, KS, (size_t)gp * NT + gt);
    double x = (double)logits[gp * NCLS + tgt_ids[gt]];
    cost[tt][p] = cost_entry(dot, (double)pnorm[gp], (double)tnorm[gt], x);
  }
  __syncthreads();
  if (t >= 64) return;

  const int lane = t;
  const int jA = lane + 1, jB = lane + 65;
  const bool hasB = (jB <= NN);

  float ca[20], cb[20];
  #pragma unroll
  for (int r = 0; r < 20; r++){
    ca[r] = cost[r][lane];
    cb[r] = hasB ? cost[r][lane + 64] : 0.f;
  }

  const float INF = 1e30f;
  float vA = 0.f, vB = 0.f;
  float uA = 0.f, uB = 0.f;
  int pA = 0, pB = 0;
  unsigned long long mAmask = 0ull, mBmask = 0ull;

  for (int i = 1; i <= MT; i++){
    float minA = INF, minB = INF;
    int wayA = 0, wayB = 0;
    bool usedA = false, usedB = false;
    float u_i = 0.f;
    int j0 = 0, i0 = i;
    float ui0 = 0.f;

    while (true){
      if (j0 != 0){
        if (j0 <= 64){ if (lane == j0 - 1)  usedA = true; }
        else         { if (lane == j0 - 65) usedB = true; }
      }
      if (!usedA){
        float cur = sel20(ca, i0 - 1) - ui0 - vA;
        if (cur < minA){ minA = cur; wayA = j0; }
      }
      if (hasB && !usedB){
        float cur = sel20(cb, i0 - 1) - ui0 - vB;
        if (cur < minB){ minB = cur; wayB = j0; }
      }
      float candA = usedA ? INF : minA;
      float candB = (hasB && !usedB) ? minB : INF;
      float v = fminf(candA, candB);
      v = dppmin(v, 0xB1);
      v = dppmin(v, 0x4E);
      v = dppmin(v, 0x124);
      v = dppmin(v, 0x128);
      v = fminf(v, __shfl_xor(v, 16));
      v = fminf(v, __shfl_xor(v, 32));
      const float delta = v;
      unsigned long long mAm = __ballot(candA == delta);
      unsigned long long mBm = __ballot(candB == delta);
      const int j1 = mAm ? __ffsll(mAm) : 64 + __ffsll(mBm);
      u_i += delta;
      if (usedA){ vA -= delta; uA += delta; } else minA -= delta;
      if (hasB){ if (usedB){ vB -= delta; uB += delta; } else minB -= delta; }
      j0 = j1;
      bool matched = (j0 <= 64) ? ((mAmask >> (j0 - 1)) & 1ull)
                                : ((mBmask >> (j0 - 65)) & 1ull);
      int   pa = __shfl(pA, (j0 - 1) & 63), pb = __shfl(pB, (j0 - 65) & 63);
      float ua = __shfl(uA, (j0 - 1) & 63), ub = __shfl(uB, (j0 - 65) & 63);
      if (!matched) break;
      i0  = (j0 <= 64) ? pa : pb;
      ui0 = (j0 <= 64) ? ua : ub;
    }
    int j = j0;
    while (true){
      int wjA = __shfl(wayA, (j - 1) & 63);
      int wjB = __shfl(wayB, (j - 65) & 63);
      int wj = (j <= 64) ? wjA : wjB;
      int pv; float uv;
      if (wj == 0){ pv = i; uv = u_i; }
      else {
        int   pa = __shfl(pA, (wj - 1) & 63), pb = __shfl(pB, (wj - 65) & 63);
        float ua = __shfl(uA, (wj - 1) & 63), ub = __shfl(uB, (wj - 65) & 63);
        pv = (wj <= 64) ? pa : pb;
        uv = (wj <= 64) ? ua : ub;
      }
      if (j <= 64){ if (lane == j - 1) { pA = pv; uA = uv; } }
      else        { if (lane == j - 65){ pB = pv; uB = uv; } }
      j = wj;
      if (j == 0) break;
    }
    mAmask = __ballot(pA != 0);
    mBmask = __ballot(hasB && pB != 0);
  }

  unsigned long long lt = (1ull << lane) - 1ull;
  if (pA != 0){
    int rank = __popcll(mAmask & lt);
    rows_out[img * MT + rank] = (float)(jA - 1);
    cols_out[img * MT + rank] = (float)(pA - 1);
  }
  if (hasB && pB != 0){
    int rank = __popcll(mAmask) + __popcll(mBmask & lt);
    rows_out[img * MT + rank] = (float)(jB - 1);
    cols_out[img * MT + rank] = (float)(pB - 1);
  }
}

extern "C" void kernel_launch(void* const* d_in, const int* in_sizes, int n_in,
                              void* d_out, int out_size, void* d_ws, size_t ws_size,
                              hipStream_t stream) {
  const float* pm     = (const float*)d_in[0];
  const float* logits = (const float*)d_in[1];
  const float* tm     = (const float*)d_in[2];
  const int*   tids   = (const int*)d_in[3];

  float* C        = (float*)d_out;
  float* rows_out = C + CNT;
  float* cols_out = rows_out + NB * MT;

  // ws: pnp[KS][800] | pnorm[800] | tnorm[160] | tnp2[320] | Bb bf16[160*25600] | part[KS][128000]
  static const int ks_opts[] = {40, 20, 10};
  int KS = 10; size_t bb_off = 0, part_off = 0;
  for (int oi = 0; oi < 3; oi++){
    int o = ks_opts[oi];
    size_t small = (size_t)o * NPRED * 4 + NPRED * 4 + NT * 4 + 2 * NT * 4;
    size_t bo = (small + 255) & ~(size_t)255;
    size_t po = (bo + (size_t)NT * HW * 2 + 255) & ~(size_t)255;
    size_t need = po + (size_t)o * CNT * 4;
    if (need <= ws_size){ KS = o; bb_off = bo; part_off = po; break; }
  }
  char* ws = (char*)d_ws;
  float* pnp         = (float*)ws;
  float* pnorm       = (float*)(ws + (size_t)KS * NPRED * 4);
  float* tnorm       = pnorm + NPRED;
  float* tnp2        = tnorm + NT;
  unsigned short* Bb = (unsigned short*)(ws + bb_off);
  float* part        = (float*)(ws + part_off);

  const int Kc = HW / KS;

  conv_b<<<2 * NT, 256, 0, stream>>>(tm, Bb, tnp2);
  if (KS == 40)      gemm_p2<10><<<MTILES * 40, 256, 0, stream>>>(pm, Bb, part, pnp, Kc);
  else if (KS == 20) gemm_p2<20><<<MTILES * 20, 256, 0, stream>>>(pm, Bb, part, pnp, Kc);
  else               gemm_p2<40><<<MTILES * 10, 256, 0, stream>>>(pm, Bb, part, pnp, Kc);
  norm_reduce<<<4, 256, 0, stream>>>(pnp, tnp2, pnorm, tnorm, KS);
  fin_hung<<<NB + 500, 256, 0, stream>>>(part, KS, pnorm, tnorm, logits, tids,
                                         C, rows_out, cols_out);
}

// Round 12
// 73.657 us; speedup vs baseline: 1.6326x; 1.5550x over previous
//
#include <hip/hip_runtime.h>
#include <math.h>

#define NB    8
#define NN    100
#define NPRED 800
#define MT    20
#define NT    160
#define HW    25600
#define NCLS  80
#define CNT   (NPRED*NT)  // 128000
#define MTILES 25         // 32-row tiles: 25*32 = 800 exactly (no bounds checks)

typedef float  f32x4  __attribute__((ext_vector_type(4)));
typedef short  short8 __attribute__((ext_vector_type(8)));
typedef unsigned short u16x8 __attribute__((ext_vector_type(8)));

static __device__ __forceinline__ unsigned short f2bf_rne(float f){
  unsigned u = __float_as_uint(f);
  return (unsigned short)((u + 0x7fffu + ((u >> 16) & 1u)) >> 16);
}

// async global->LDS, 16B per lane
static __device__ __forceinline__ void gload16(const void* g, void* l){
  __builtin_amdgcn_global_load_lds((const __attribute__((address_space(1))) unsigned int*)g,
                                   (__attribute__((address_space(3))) unsigned int*)l, 16, 0, 0);
}

// ---------------- pre-pass: tm fp32 -> bf16 with BAKED XOR swizzle, half-row partial tnorm ----------------
__global__ __launch_bounds__(256)
void conv_b(const float* __restrict__ tm, unsigned short* __restrict__ Bb,
            float* __restrict__ tnp2){
  const int row = blockIdx.x >> 1, half = blockIdx.x & 1;
  const float4* src = (const float4*)(tm + (size_t)row * HW);
  u16x8* dst = (u16x8*)(Bb + (size_t)row * HW);
  const int sw = row & 7;
  const int g0 = half * 1600, g1 = g0 + 1600;
  float s = 0.f;
  for (int g = g0 + threadIdx.x; g < g1; g += 256){
    float4 x0 = src[g * 2], x1 = src[g * 2 + 1];
    float v[8];
    v[0]=x0.x; v[1]=x0.y; v[2]=x0.z; v[3]=x0.w;
    v[4]=x1.x; v[5]=x1.y; v[6]=x1.z; v[7]=x1.w;
    u16x8 h;
    #pragma unroll
    for (int i = 0; i < 8; i++){ s += v[i]*v[i]; h[i] = f2bf_rne(v[i]); }
    dst[(g & ~7) | ((g & 7) ^ sw)] = h;
  }
  __shared__ float red[256];
  red[threadIdx.x] = s; __syncthreads();
  for (int off = 128; off > 0; off >>= 1){
    if (threadIdx.x < off) red[threadIdx.x] += red[threadIdx.x + off];
    __syncthreads();
  }
  if (threadIdx.x == 0) tnp2[half * NT + row] = red[0];
}

// ---------------- hybrid GEMM, 32-row tiles for CU residency ----------------
// Tile 32x160x64; 4 waves 2x2, wave tile 16x80 (1x5 frags of 16x16x32 bf16).
// LDS 24 KiB -> ~6 blocks/CU; grid 1000 -> ~4/CU co-resident (cross-block overlap).
// B via global_load_lds (swizzle baked in Bb); A fp32->cvt->swizzled ds_write.
template<int KSTEPS>
__global__ __launch_bounds__(256, 6)
void gemm_hyb(const float* __restrict__ A, const unsigned short* __restrict__ Bb,
              float* __restrict__ part, float* __restrict__ pnp, int Kc){
  __shared__ unsigned short sA[32*64];    // 4 KB
  __shared__ unsigned short sB[160*64];   // 20 KB

  const int bid = blockIdx.x;
  const int nb  = gridDim.x;
  const int wg  = ((nb & 7) == 0) ? (bid & 7) * (nb >> 3) + (bid >> 3) : bid;  // XCD-bijective
  const int mtile = wg % MTILES, ks = wg / MTILES;
  const int t = threadIdx.x, lane = t & 63, w = t >> 6;
  const int wr = w >> 1, wc = w & 1;
  const int fr = lane & 15, fq = lane >> 4;
  const int arow = t >> 3, ksl = t & 7;    // A staging: 32 rows x 8 slots = 256
  const int kbase = ks * Kc;

  f32x4 acc[5];
  #pragma unroll
  for (int c = 0; c < 5; c++) acc[c] = (f32x4){0.f,0.f,0.f,0.f};
  float asum = 0.f;

  // B slot descriptors: 1280 granules, 5 per thread
  int brow[5], bg[5];
  #pragma unroll
  for (int i = 0; i < 5; i++){ int s2 = t + i * 256; brow[i] = s2 >> 3; bg[i] = s2 & 7; }

  const float4* ap = (const float4*)(A + (size_t)(mtile*32 + arow) * HW + kbase + ksl * 8);

  for (int step = 0; step < KSTEPS; ++step){
    const int k0 = kbase + step * 64;
    // ---- B: direct DMA to linear LDS (swizzle baked in memory) ----
    #pragma unroll
    for (int i = 0; i < 5; i++)
      gload16(Bb + (size_t)brow[i] * HW + k0 + bg[i] * 8, sB + (t + i * 256) * 8);
    // ---- A: fp32 load -> cvt -> swizzled ds_write (1 granule/thread) ----
    {
      float4 x0 = ap[step * 16];
      float4 x1 = ap[step * 16 + 1];
      float v[8];
      v[0]=x0.x; v[1]=x0.y; v[2]=x0.z; v[3]=x0.w;
      v[4]=x1.x; v[5]=x1.y; v[6]=x1.z; v[7]=x1.w;
      u16x8 h;
      #pragma unroll
      for (int i = 0; i < 8; i++){ asum += v[i]*v[i]; h[i] = f2bf_rne(v[i]); }
      *(u16x8*)&sA[arow * 64 + ((ksl ^ (arow & 7)) << 3)] = h;
    }
    __syncthreads();   // drains vmcnt (B DMA) + lgkmcnt (A writes)
    // ---- MFMA: 2 kk halves x (1x5 frags) ----
    #pragma unroll
    for (int kk = 0; kk < 2; ++kk){
      const int swz = (((kk * 4 + fq) ^ (fr & 7)) << 3);
      short8 a = *(const short8*)&sA[(wr*16 + fr) * 64 + swz];
      short8 b[5];
      #pragma unroll
      for (int c = 0; c < 5; c++)
        b[c] = *(const short8*)&sB[(wc*80 + c*16 + fr) * 64 + swz];
      #pragma unroll
      for (int c = 0; c < 5; c++)
        acc[c] = __builtin_amdgcn_mfma_f32_16x16x32_bf16(a, b[c], acc[c], 0, 0, 0);
    }
    __syncthreads();
  }

  // ---- pnorm partials: reduce over ksl lanes ----
  {
    float s = asum;
    s += __shfl_xor(s, 1); s += __shfl_xor(s, 2); s += __shfl_xor(s, 4);
    if ((t & 7) == 0) pnp[(size_t)ks * NPRED + mtile*32 + arow] = s;
  }

  // ---- store partials ----
  float* dst = part + (size_t)ks * CNT;
  #pragma unroll
  for (int c = 0; c < 5; c++)
    #pragma unroll
    for (int i = 0; i < 4; i++){
      const int grow = mtile*32 + wr*16 + fq*4 + i;
      dst[(size_t)grow * NT + wc*80 + c*16 + fr] = acc[c][i];
    }
}

// ---------------- reduce pnorm partials + tnorm halves ----------------
__global__ __launch_bounds__(256) void norm_reduce(const float* __restrict__ pnp,
                                                   const float* __restrict__ tnp2,
                                                   float* __restrict__ pn,
                                                   float* __restrict__ tn, int KS){
  int idx = blockIdx.x * 256 + threadIdx.x;
  if (idx < NPRED){
    float s = 0.f;
    for (int ks = 0; ks < KS; ks++) s += pnp[(size_t)ks * NPRED + idx];
    pn[idx] = s;
  } else if (idx < NPRED + NT){
    int j = idx - NPRED;
    tn[j] = tnp2[j] + tnp2[NT + j];
  }
}

// ---------------- finalize: reduce K-splits, dice + focal class cost ----------------
__global__ __launch_bounds__(256) void finalize(const float* __restrict__ part, int KS,
                                                const float* __restrict__ pnorm,
                                                const float* __restrict__ tnorm,
                                                const float* __restrict__ logits,
                                                const int* __restrict__ tgt_ids,
                                                float* __restrict__ C){
  int idx = blockIdx.x * 256 + threadIdx.x;
  int pred = idx / NT, tt = idx - pred * NT;
  const float* p = part + idx;
  double d0=0.0, d1=0.0, d2=0.0, d3=0.0;
  int ks = 0;
  for (; ks + 4 <= KS; ks += 4){
    d0 += (double)p[(size_t)(ks+0) * CNT];
    d1 += (double)p[(size_t)(ks+1) * CNT];
    d2 += (double)p[(size_t)(ks+2) * CNT];
    d3 += (double)p[(size_t)(ks+3) * CNT];
  }
  for (; ks < KS; ks++) d0 += (double)p[(size_t)ks * CNT];
  double dot = (d0 + d1) + (d2 + d3);
  double num = 2.0 * dot;
  double den = (double)pnorm[pred] + (double)tnorm[tt];
  double mask_score = -((num + 1e-4) / (den + 1e-4));
  double x = (double)logits[pred * NCLS + tgt_ids[tt]];
  double pl = 1.0 / (1.0 + exp(-x));
  double pos = 0.25 * (1.0 - pl) * (1.0 - pl) * (-log(pl + 1e-8));
  double neg = 0.75 * pl * pl * (-log(1.0 - pl + 1e-8));
  double cv = mask_score * 2.0 + (pos - neg);
  float o = (float)cv;
  if (!isfinite(o)) o = 0.0f;
  C[idx] = o;
}

// ---------------- Hungarian (JV): fp32 regs, DPP min + ballot argmin, packed (p,u) ----------------
static __device__ __forceinline__ float sel20(const float c[20], int k){
  const bool b0 = k & 1, b1 = k & 2;
  float t0 = b0 ? c[1]  : c[0],  t1 = b0 ? c[3]  : c[2];
  float t2 = b0 ? c[5]  : c[4],  t3 = b0 ? c[7]  : c[6];
  float t4 = b0 ? c[9]  : c[8],  t5 = b0 ? c[11] : c[10];
  float t6 = b0 ? c[13] : c[12], t7 = b0 ? c[15] : c[14];
  float t8 = b0 ? c[17] : c[16], t9 = b0 ? c[19] : c[18];
  float e0 = b1 ? t1 : t0, e1 = b1 ? t3 : t2, e2 = b1 ? t5 : t4;
  float e3 = b1 ? t7 : t6, e4 = b1 ? t9 : t8;
  const int hi = k >> 2;
  const bool h0 = hi & 1, h1 = hi & 2, h2 = hi & 4;
  float g0 = h0 ? e1 : e0, g1 = h0 ? e3 : e2;
  float m0 = h1 ? g1 : g0;
  return h2 ? e4 : m0;
}

static __device__ __forceinline__ float dppmin(float v, int ctrl){
  int x;
  switch (ctrl){
    case 0xB1:  x = __builtin_amdgcn_update_dpp(0, __float_as_int(v), 0xB1,  0xF, 0xF, true); break;
    case 0x4E:  x = __builtin_amdgcn_update_dpp(0, __float_as_int(v), 0x4E,  0xF, 0xF, true); break;
    case 0x124: x = __builtin_amdgcn_update_dpp(0, __float_as_int(v), 0x124, 0xF, 0xF, true); break;
    default:    x = __builtin_amdgcn_update_dpp(0, __float_as_int(v), 0x128, 0xF, 0xF, true); break;
  }
  return fminf(v, __int_as_float(x));
}

__global__ __launch_bounds__(64) void hungarian(const float* __restrict__ C,
                                                float* __restrict__ rows_out,
                                                float* __restrict__ cols_out){
  const int img  = blockIdx.x;
  const int lane = threadIdx.x;
  const int jA = lane + 1, jB = lane + 65;
  const bool hasB = (jB <= NN);

  float ca[20], cb[20];
  {
    const float* basep = C + (size_t)img * NN * NT + (size_t)lane * NT + img * MT;
    #pragma unroll
    for (int r = 0; r < 5; r++){
      float4 x = *(const float4*)(basep + r*4);
      ca[r*4+0]=x.x; ca[r*4+1]=x.y; ca[r*4+2]=x.z; ca[r*4+3]=x.w;
    }
    if (hasB){
      const float* basep2 = basep + (size_t)64 * NT;
      #pragma unroll
      for (int r = 0; r < 5; r++){
        float4 x = *(const float4*)(basep2 + r*4);
        cb[r*4+0]=x.x; cb[r*4+1]=x.y; cb[r*4+2]=x.z; cb[r*4+3]=x.w;
      }
    } else {
      #pragma unroll
      for (int r = 0; r < 20; r++) cb[r] = 0.f;
    }
  }

  const float INF = 1e30f;
  float vA = 0.f, vB = 0.f;
  float uA = 0.f, uB = 0.f;
  int pA = 0, pB = 0;
  unsigned long long mAmask = 0ull, mBmask = 0ull;

  for (int i = 1; i <= MT; i++){
    float minA = INF, minB = INF;
    int wayA = 0, wayB = 0;
    bool usedA = false, usedB = false;
    float u_i = 0.f;
    int j0 = 0, i0 = i;
    float ui0 = 0.f;

    while (true){
      if (j0 != 0){
        if (j0 <= 64){ if (lane == j0 - 1)  usedA = true; }
        else         { if (lane == j0 - 65) usedB = true; }
      }
      if (!usedA){
        float cur = sel20(ca, i0 - 1) - ui0 - vA;
        if (cur < minA){ minA = cur; wayA = j0; }
      }
      if (hasB && !usedB){
        float cur = sel20(cb, i0 - 1) - ui0 - vB;
        if (cur < minB){ minB = cur; wayB = j0; }
      }
      float candA = usedA ? INF : minA;
      float candB = (hasB && !usedB) ? minB : INF;
      float v = fminf(candA, candB);
      v = dppmin(v, 0xB1);
      v = dppmin(v, 0x4E);
      v = dppmin(v, 0x124);
      v = dppmin(v, 0x128);
      v = fminf(v, __shfl_xor(v, 16));
      v = fminf(v, __shfl_xor(v, 32));
      const float delta = v;
      unsigned long long mAm = __ballot(candA == delta);
      unsigned long long mBm = __ballot(candB == delta);
      const int j1 = mAm ? __ffsll(mAm) : 64 + __ffsll(mBm);
      u_i += delta;
      if (usedA){ vA -= delta; uA += delta; } else minA -= delta;
      if (hasB){ if (usedB){ vB -= delta; uB += delta; } else minB -= delta; }
      j0 = j1;
      bool matched = (j0 <= 64) ? ((mAmask >> (j0 - 1)) & 1ull)
                                : ((mBmask >> (j0 - 65)) & 1ull);
      int   pa = __shfl(pA, (j0 - 1) & 63), pb = __shfl(pB, (j0 - 65) & 63);
      float ua = __shfl(uA, (j0 - 1) & 63), ub = __shfl(uB, (j0 - 65) & 63);
      if (!matched) break;
      i0  = (j0 <= 64) ? pa : pb;
      ui0 = (j0 <= 64) ? ua : ub;
    }
    int j = j0;
    while (true){
      int wjA = __shfl(wayA, (j - 1) & 63);
      int wjB = __shfl(wayB, (j - 65) & 63);
      int wj = (j <= 64) ? wjA : wjB;
      int pv; float uv;
      if (wj == 0){ pv = i; uv = u_i; }
      else {
        int   pa = __shfl(pA, (wj - 1) & 63), pb = __shfl(pB, (wj - 65) & 63);
        float ua = __shfl(uA, (wj - 1) & 63), ub = __shfl(uB, (wj - 65) & 63);
        pv = (wj <= 64) ? pa : pb;
        uv = (wj <= 64) ? ua : ub;
      }
      if (j <= 64){ if (lane == j - 1) { pA = pv; uA = uv; } }
      else        { if (lane == j - 65){ pB = pv; uB = uv; } }
      j = wj;
      if (j == 0) break;
    }
    mAmask = __ballot(pA != 0);
    mBmask = __ballot(hasB && pB != 0);
  }

  unsigned long long lt = (1ull << lane) - 1ull;
  if (pA != 0){
    int rank = __popcll(mAmask & lt);
    rows_out[img * MT + rank] = (float)(jA - 1);
    cols_out[img * MT + rank] = (float)(pA - 1);
  }
  if (hasB && pB != 0){
    int rank = __popcll(mAmask) + __popcll(mBmask & lt);
    rows_out[img * MT + rank] = (float)(jB - 1);
    cols_out[img * MT + rank] = (float)(pB - 1);
  }
}

extern "C" void kernel_launch(void* const* d_in, const int* in_sizes, int n_in,
                              void* d_out, int out_size, void* d_ws, size_t ws_size,
                              hipStream_t stream) {
  const float* pm     = (const float*)d_in[0];
  const float* logits = (const float*)d_in[1];
  const float* tm     = (const float*)d_in[2];
  const int*   tids   = (const int*)d_in[3];

  float* C        = (float*)d_out;
  float* rows_out = C + CNT;
  float* cols_out = rows_out + NB * MT;

  // ws: pnp[KS][800] | pnorm[800] | tnorm[160] | tnp2[320] | Bb bf16[160*25600] | part[KS][128000]
  static const int ks_opts[] = {40, 20, 10};
  int KS = 10; size_t bb_off = 0, part_off = 0;
  for (int oi = 0; oi < 3; oi++){
    int o = ks_opts[oi];
    size_t small = (size_t)o * NPRED * 4 + NPRED * 4 + NT * 4 + 2 * NT * 4;
    size_t bo = (small + 255) & ~(size_t)255;
    size_t po = (bo + (size_t)NT * HW * 2 + 255) & ~(size_t)255;
    size_t need = po + (size_t)o * CNT * 4;
    if (need <= ws_size){ KS = o; bb_off = bo; part_off = po; break; }
  }
  char* ws = (char*)d_ws;
  float* pnp         = (float*)ws;
  float* pnorm       = (float*)(ws + (size_t)KS * NPRED * 4);
  float* tnorm       = pnorm + NPRED;
  float* tnp2        = tnorm + NT;
  unsigned short* Bb = (unsigned short*)(ws + bb_off);
  float* part        = (float*)(ws + part_off);

  const int Kc = HW / KS;

  conv_b<<<2 * NT, 256, 0, stream>>>(tm, Bb, tnp2);
  if (KS == 40)      gemm_hyb<10><<<MTILES * 40, 256, 0, stream>>>(pm, Bb, part, pnp, Kc);
  else if (KS == 20) gemm_hyb<20><<<MTILES * 20, 256, 0, stream>>>(pm, Bb, part, pnp, Kc);
  else               gemm_hyb<40><<<MTILES * 10, 256, 0, stream>>>(pm, Bb, part, pnp, Kc);
  norm_reduce<<<4, 256, 0, stream>>>(pnp, tnp2, pnorm, tnorm, KS);
  finalize<<<500, 256, 0, stream>>>(part, KS, pnorm, tnorm, logits, tids, C);
  hungarian<<<NB, 64, 0, stream>>>(C, rows_out, cols_out);
}

// Round 13
// 71.258 us; speedup vs baseline: 1.6876x; 1.0337x over previous
//
#include <hip/hip_runtime.h>
#include <math.h>

#define NB    8
#define NN    100
#define NPRED 800
#define MT    20
#define NT    160
#define HW    25600
#define NCLS  80
#define CNT   (NPRED*NT)  // 128000
#define MTILES 25         // 32-row tiles: 25*32 = 800 exactly

typedef float  f32x4  __attribute__((ext_vector_type(4)));
typedef short  short8 __attribute__((ext_vector_type(8)));
typedef unsigned short u16x8 __attribute__((ext_vector_type(8)));

static __device__ __forceinline__ unsigned short f2bf_rne(float f){
  unsigned u = __float_as_uint(f);
  return (unsigned short)((u + 0x7fffu + ((u >> 16) & 1u)) >> 16);
}
static __device__ __forceinline__ float bf2f(unsigned short h){
  return __uint_as_float(((unsigned)h) << 16);
}

// async global->LDS, 16B per lane
static __device__ __forceinline__ void gload16(const void* g, void* l){
  __builtin_amdgcn_global_load_lds((const __attribute__((address_space(1))) unsigned int*)g,
                                   (__attribute__((address_space(3))) unsigned int*)l, 16, 0, 0);
}

// ---------------- pre-pass: tm fp32 -> bf16 with BAKED XOR swizzle, half-row partial tnorm ----------------
__global__ __launch_bounds__(256)
void conv_b(const float* __restrict__ tm, unsigned short* __restrict__ Bb,
            float* __restrict__ tnp2){
  const int row = blockIdx.x >> 1, half = blockIdx.x & 1;
  const float4* src = (const float4*)(tm + (size_t)row * HW);
  u16x8* dst = (u16x8*)(Bb + (size_t)row * HW);
  const int sw = row & 7;
  const int g0 = half * 1600, g1 = g0 + 1600;
  float s = 0.f;
  for (int g = g0 + threadIdx.x; g < g1; g += 256){
    float4 x0 = src[g * 2], x1 = src[g * 2 + 1];
    float v[8];
    v[0]=x0.x; v[1]=x0.y; v[2]=x0.z; v[3]=x0.w;
    v[4]=x1.x; v[5]=x1.y; v[6]=x1.z; v[7]=x1.w;
    u16x8 h;
    #pragma unroll
    for (int i = 0; i < 8; i++){ s += v[i]*v[i]; h[i] = f2bf_rne(v[i]); }
    dst[(g & ~7) | ((g & 7) ^ sw)] = h;
  }
  __shared__ float red[256];
  red[threadIdx.x] = s; __syncthreads();
  for (int off = 128; off > 0; off >>= 1){
    if (threadIdx.x < off) red[threadIdx.x] += red[threadIdx.x + off];
    __syncthreads();
  }
  if (threadIdx.x == 0) tnp2[half * NT + row] = red[0];
}

// ---------------- hybrid GEMM, 32-row tiles, bf16 part store ----------------
// Tile 32x160x64; 4 waves 2x2, wave tile 16x80. LDS 24 KiB. Grid 1000 (~4/CU).
template<int KSTEPS>
__global__ __launch_bounds__(256, 6)
void gemm_hyb(const float* __restrict__ A, const unsigned short* __restrict__ Bb,
              unsigned short* __restrict__ partb, float* __restrict__ pnp, int Kc){
  __shared__ unsigned short sA[32*64];    // 4 KB
  __shared__ unsigned short sB[160*64];   // 20 KB

  const int bid = blockIdx.x;
  const int nb  = gridDim.x;
  const int wg  = ((nb & 7) == 0) ? (bid & 7) * (nb >> 3) + (bid >> 3) : bid;  // XCD-bijective
  const int mtile = wg % MTILES, ks = wg / MTILES;
  const int t = threadIdx.x, lane = t & 63, w = t >> 6;
  const int wr = w >> 1, wc = w & 1;
  const int fr = lane & 15, fq = lane >> 4;
  const int arow = t >> 3, ksl = t & 7;    // A staging: 32 rows x 8 slots
  const int kbase = ks * Kc;

  f32x4 acc[5];
  #pragma unroll
  for (int c = 0; c < 5; c++) acc[c] = (f32x4){0.f,0.f,0.f,0.f};
  float asum = 0.f;

  int brow[5], bg[5];
  #pragma unroll
  for (int i = 0; i < 5; i++){ int s2 = t + i * 256; brow[i] = s2 >> 3; bg[i] = s2 & 7; }

  const float4* ap = (const float4*)(A + (size_t)(mtile*32 + arow) * HW + kbase + ksl * 8);

  for (int step = 0; step < KSTEPS; ++step){
    const int k0 = kbase + step * 64;
    #pragma unroll
    for (int i = 0; i < 5; i++)
      gload16(Bb + (size_t)brow[i] * HW + k0 + bg[i] * 8, sB + (t + i * 256) * 8);
    {
      float4 x0 = ap[step * 16];
      float4 x1 = ap[step * 16 + 1];
      float v[8];
      v[0]=x0.x; v[1]=x0.y; v[2]=x0.z; v[3]=x0.w;
      v[4]=x1.x; v[5]=x1.y; v[6]=x1.z; v[7]=x1.w;
      u16x8 h;
      #pragma unroll
      for (int i = 0; i < 8; i++){ asum += v[i]*v[i]; h[i] = f2bf_rne(v[i]); }
      *(u16x8*)&sA[arow * 64 + ((ksl ^ (arow & 7)) << 3)] = h;
    }
    __syncthreads();
    #pragma unroll
    for (int kk = 0; kk < 2; ++kk){
      const int swz = (((kk * 4 + fq) ^ (fr & 7)) << 3);
      short8 a = *(const short8*)&sA[(wr*16 + fr) * 64 + swz];
      short8 b[5];
      #pragma unroll
      for (int c = 0; c < 5; c++)
        b[c] = *(const short8*)&sB[(wc*80 + c*16 + fr) * 64 + swz];
      #pragma unroll
      for (int c = 0; c < 5; c++)
        acc[c] = __builtin_amdgcn_mfma_f32_16x16x32_bf16(a, b[c], acc[c], 0, 0, 0);
    }
    __syncthreads();
  }

  // pnorm partials
  {
    float s = asum;
    s += __shfl_xor(s, 1); s += __shfl_xor(s, 2); s += __shfl_xor(s, 4);
    if ((t & 7) == 0) pnp[(size_t)ks * NPRED + mtile*32 + arow] = s;
  }

  // store partials as bf16 (halves part traffic; error ~2e-5 on C, negligible)
  unsigned short* dst = partb + (size_t)ks * CNT;
  #pragma unroll
  for (int c = 0; c < 5; c++)
    #pragma unroll
    for (int i = 0; i < 4; i++){
      const int grow = mtile*32 + wr*16 + fq*4 + i;
      dst[(size_t)grow * NT + wc*80 + c*16 + fr] = f2bf_rne(acc[c][i]);
    }
}

// ---------------- finalize: fused norm reduce + K-split reduce + dice + focal cost ----------------
__global__ __launch_bounds__(256) void finalize(const unsigned short* __restrict__ partb, int KS,
                                                const float* __restrict__ pnp,
                                                const float* __restrict__ tnp2,
                                                const float* __restrict__ logits,
                                                const int* __restrict__ tgt_ids,
                                                float* __restrict__ C){
  __shared__ float stn[NT];
  __shared__ float spn[4];
  const int blk = blockIdx.x, t = threadIdx.x;
  const int idx0 = blk * 256;
  const int p0 = idx0 / NT;
  const int pcnt = (idx0 + 255) / NT - p0 + 1;    // <= 3
  if (t < NT){
    stn[t] = tnp2[t] + tnp2[NT + t];
  } else if (t < NT + pcnt){
    const int p = p0 + (t - NT);
    float s = 0.f;
    for (int ks = 0; ks < KS; ks++) s += pnp[(size_t)ks * NPRED + p];
    spn[t - NT] = s;
  }
  __syncthreads();

  const int idx = idx0 + t;
  const int pred = idx / NT, tt = idx - pred * NT;
  const unsigned short* p = partb + idx;
  double d0=0.0, d1=0.0, d2=0.0, d3=0.0;
  int ks = 0;
  for (; ks + 4 <= KS; ks += 4){
    d0 += (double)bf2f(p[(size_t)(ks+0) * CNT]);
    d1 += (double)bf2f(p[(size_t)(ks+1) * CNT]);
    d2 += (double)bf2f(p[(size_t)(ks+2) * CNT]);
    d3 += (double)bf2f(p[(size_t)(ks+3) * CNT]);
  }
  for (; ks < KS; ks++) d0 += (double)bf2f(p[(size_t)ks * CNT]);
  double dot = (d0 + d1) + (d2 + d3);
  double num = 2.0 * dot;
  double den = (double)spn[pred - p0] + (double)stn[tt];
  double mask_score = -((num + 1e-4) / (den + 1e-4));
  double x = (double)logits[pred * NCLS + tgt_ids[tt]];
  double pl = 1.0 / (1.0 + exp(-x));
  double pos = 0.25 * (1.0 - pl) * (1.0 - pl) * (-log(pl + 1e-8));
  double neg = 0.75 * pl * pl * (-log(1.0 - pl + 1e-8));
  double cv = mask_score * 2.0 + (pos - neg);
  float o = (float)cv;
  if (!isfinite(o)) o = 0.0f;
  C[idx] = o;
}

// ---------------- Hungarian (JV): fp32 regs, DPP min + ballot argmin, packed (p,u) ----------------
static __device__ __forceinline__ float sel20(const float c[20], int k){
  const bool b0 = k & 1, b1 = k & 2;
  float t0 = b0 ? c[1]  : c[0],  t1 = b0 ? c[3]  : c[2];
  float t2 = b0 ? c[5]  : c[4],  t3 = b0 ? c[7]  : c[6];
  float t4 = b0 ? c[9]  : c[8],  t5 = b0 ? c[11] : c[10];
  float t6 = b0 ? c[13] : c[12], t7 = b0 ? c[15] : c[14];
  float t8 = b0 ? c[17] : c[16], t9 = b0 ? c[19] : c[18];
  float e0 = b1 ? t1 : t0, e1 = b1 ? t3 : t2, e2 = b1 ? t5 : t4;
  float e3 = b1 ? t7 : t6, e4 = b1 ? t9 : t8;
  const int hi = k >> 2;
  const bool h0 = hi & 1, h1 = hi & 2, h2 = hi & 4;
  float g0 = h0 ? e1 : e0, g1 = h0 ? e3 : e2;
  float m0 = h1 ? g1 : g0;
  return h2 ? e4 : m0;
}

static __device__ __forceinline__ float dppmin(float v, int ctrl){
  int x;
  switch (ctrl){
    case 0xB1:  x = __builtin_amdgcn_update_dpp(0, __float_as_int(v), 0xB1,  0xF, 0xF, true); break;
    case 0x4E:  x = __builtin_amdgcn_update_dpp(0, __float_as_int(v), 0x4E,  0xF, 0xF, true); break;
    case 0x124: x = __builtin_amdgcn_update_dpp(0, __float_as_int(v), 0x124, 0xF, 0xF, true); break;
    default:    x = __builtin_amdgcn_update_dpp(0, __float_as_int(v), 0x128, 0xF, 0xF, true); break;
  }
  return fminf(v, __int_as_float(x));
}

__global__ __launch_bounds__(64) void hungarian(const float* __restrict__ C,
                                                float* __restrict__ rows_out,
                                                float* __restrict__ cols_out){
  const int img  = blockIdx.x;
  const int lane = threadIdx.x;
  const int jA = lane + 1, jB = lane + 65;
  const bool hasB = (jB <= NN);

  float ca[20], cb[20];
  {
    const float* basep = C + (size_t)img * NN * NT + (size_t)lane * NT + img * MT;
    #pragma unroll
    for (int r = 0; r < 5; r++){
      float4 x = *(const float4*)(basep + r*4);
      ca[r*4+0]=x.x; ca[r*4+1]=x.y; ca[r*4+2]=x.z; ca[r*4+3]=x.w;
    }
    if (hasB){
      const float* basep2 = basep + (size_t)64 * NT;
      #pragma unroll
      for (int r = 0; r < 5; r++){
        float4 x = *(const float4*)(basep2 + r*4);
        cb[r*4+0]=x.x; cb[r*4+1]=x.y; cb[r*4+2]=x.z; cb[r*4+3]=x.w;
      }
    } else {
      #pragma unroll
      for (int r = 0; r < 20; r++) cb[r] = 0.f;
    }
  }

  const float INF = 1e30f;
  float vA = 0.f, vB = 0.f;
  float uA = 0.f, uB = 0.f;
  int pA = 0, pB = 0;
  unsigned long long mAmask = 0ull, mBmask = 0ull;

  for (int i = 1; i <= MT; i++){
    float minA = INF, minB = INF;
    int wayA = 0, wayB = 0;
    bool usedA = false, usedB = false;
    float u_i = 0.f;
    int j0 = 0, i0 = i;
    float ui0 = 0.f;

    while (true){
      if (j0 != 0){
        if (j0 <= 64){ if (lane == j0 - 1)  usedA = true; }
        else         { if (lane == j0 - 65) usedB = true; }
      }
      if (!usedA){
        float cur = sel20(ca, i0 - 1) - ui0 - vA;
        if (cur < minA){ minA = cur; wayA = j0; }
      }
      if (hasB && !usedB){
        float cur = sel20(cb, i0 - 1) - ui0 - vB;
        if (cur < minB){ minB = cur; wayB = j0; }
      }
      float candA = usedA ? INF : minA;
      float candB = (hasB && !usedB) ? minB : INF;
      float v = fminf(candA, candB);
      v = dppmin(v, 0xB1);
      v = dppmin(v, 0x4E);
      v = dppmin(v, 0x124);
      v = dppmin(v, 0x128);
      v = fminf(v, __shfl_xor(v, 16));
      v = fminf(v, __shfl_xor(v, 32));
      const float delta = v;
      unsigned long long mAm = __ballot(candA == delta);
      unsigned long long mBm = __ballot(candB == delta);
      const int j1 = mAm ? __ffsll(mAm) : 64 + __ffsll(mBm);
      u_i += delta;
      if (usedA){ vA -= delta; uA += delta; } else minA -= delta;
      if (hasB){ if (usedB){ vB -= delta; uB += delta; } else minB -= delta; }
      j0 = j1;
      bool matched = (j0 <= 64) ? ((mAmask >> (j0 - 1)) & 1ull)
                                : ((mBmask >> (j0 - 65)) & 1ull);
      int   pa = __shfl(pA, (j0 - 1) & 63), pb = __shfl(pB, (j0 - 65) & 63);
      float ua = __shfl(uA, (j0 - 1) & 63), ub = __shfl(uB, (j0 - 65) & 63);
      if (!matched) break;
      i0  = (j0 <= 64) ? pa : pb;
      ui0 = (j0 <= 64) ? ua : ub;
    }
    int j = j0;
    while (true){
      int wjA = __shfl(wayA, (j - 1) & 63);
      int wjB = __shfl(wayB, (j - 65) & 63);
      int wj = (j <= 64) ? wjA : wjB;
      int pv; float uv;
      if (wj == 0){ pv = i; uv = u_i; }
      else {
        int   pa = __shfl(pA, (wj - 1) & 63), pb = __shfl(pB, (wj - 65) & 63);
        float ua = __shfl(uA, (wj - 1) & 63), ub = __shfl(uB, (wj - 65) & 63);
        pv = (wj <= 64) ? pa : pb;
        uv = (wj <= 64) ? ua : ub;
      }
      if (j <= 64){ if (lane == j - 1) { pA = pv; uA = uv; } }
      else        { if (lane == j - 65){ pB = pv; uB = uv; } }
      j = wj;
      if (j == 0) break;
    }
    mAmask = __ballot(pA != 0);
    mBmask = __ballot(hasB && pB != 0);
  }

  unsigned long long lt = (1ull << lane) - 1ull;
  if (pA != 0){
    int rank = __popcll(mAmask & lt);
    rows_out[img * MT + rank] = (float)(jA - 1);
    cols_out[img * MT + rank] = (float)(pA - 1);
  }
  if (hasB && pB != 0){
    int rank = __popcll(mAmask) + __popcll(mBmask & lt);
    rows_out[img * MT + rank] = (float)(jB - 1);
    cols_out[img * MT + rank] = (float)(pB - 1);
  }
}

extern "C" void kernel_launch(void* const* d_in, const int* in_sizes, int n_in,
                              void* d_out, int out_size, void* d_ws, size_t ws_size,
                              hipStream_t stream) {
  const float* pm     = (const float*)d_in[0];
  const float* logits = (const float*)d_in[1];
  const float* tm     = (const float*)d_in[2];
  const int*   tids   = (const int*)d_in[3];

  float* C        = (float*)d_out;
  float* rows_out = C + CNT;
  float* cols_out = rows_out + NB * MT;

  // ws: pnp[KS][800] f32 | tnp2[320] f32 | Bb bf16[160*25600] | partb bf16[KS][128000]
  static const int ks_opts[] = {40, 20, 10};
  int KS = 10; size_t bb_off = 0, part_off = 0;
  for (int oi = 0; oi < 3; oi++){
    int o = ks_opts[oi];
    size_t small = (size_t)o * NPRED * 4 + 2 * NT * 4;
    size_t bo = (small + 255) & ~(size_t)255;
    size_t po = (bo + (size_t)NT * HW * 2 + 255) & ~(size_t)255;
    size_t need = po + (size_t)o * CNT * 2;
    if (need <= ws_size){ KS = o; bb_off = bo; part_off = po; break; }
  }
  char* ws = (char*)d_ws;
  float* pnp           = (float*)ws;
  float* tnp2          = (float*)(ws + (size_t)KS * NPRED * 4);
  unsigned short* Bb   = (unsigned short*)(ws + bb_off);
  unsigned short* partb= (unsigned short*)(ws + part_off);

  const int Kc = HW / KS;

  conv_b<<<2 * NT, 256, 0, stream>>>(tm, Bb, tnp2);
  if (KS == 40)      gemm_hyb<10><<<MTILES * 40, 256, 0, stream>>>(pm, Bb, partb, pnp, Kc);
  else if (KS == 20) gemm_hyb<20><<<MTILES * 20, 256, 0, stream>>>(pm, Bb, partb, pnp, Kc);
  else               gemm_hyb<40><<<MTILES * 10, 256, 0, stream>>>(pm, Bb, partb, pnp, Kc);
  finalize<<<500, 256, 0, stream>>>(partb, KS, pnp, tnp2, logits, tids, C);
  hungarian<<<NB, 64, 0, stream>>>(C, rows_out, cols_out);
}